// Round 1
// baseline (954.354 us; speedup 1.0000x reference)
//
#include <hip/hip_runtime.h>

#define NN 100000
#define NE 1600000
#define INDIM 128
#define HID 64
#define NG 1024
#define BN_EPS 1e-5f

// ---------------- graph preprocessing ----------------

__global__ void k_deg(const int* __restrict__ col, int* __restrict__ deg, int E) {
    int e = blockIdx.x * blockDim.x + threadIdx.x;
    if (e < E) atomicAdd(&deg[col[e]], 1);
}

__global__ void k_dinv(const int* __restrict__ deg, float* __restrict__ dinv, int N) {
    int i = blockIdx.x * blockDim.x + threadIdx.x;
    if (i < N) dinv[i] = rsqrtf((float)(deg[i] + 1));  // +1 = self-loop
}

__global__ void k_scan1(const int* __restrict__ deg, int* __restrict__ bsums, int N) {
    __shared__ int s[256];
    int i = blockIdx.x * 256 + threadIdx.x;
    s[threadIdx.x] = (i < N) ? deg[i] : 0;
    __syncthreads();
    for (int off = 128; off > 0; off >>= 1) {
        if (threadIdx.x < off) s[threadIdx.x] += s[threadIdx.x + off];
        __syncthreads();
    }
    if (threadIdx.x == 0) bsums[blockIdx.x] = s[0];
}

__global__ void k_scan2(int* __restrict__ bsums, int nb, int* __restrict__ offs, int N, int E) {
    __shared__ int s[512];
    int t = threadIdx.x;
    int v = (t < nb) ? bsums[t] : 0;
    s[t] = v;
    __syncthreads();
    for (int off = 1; off < 512; off <<= 1) {
        int add = (t >= off) ? s[t - off] : 0;
        __syncthreads();
        s[t] += add;
        __syncthreads();
    }
    if (t < nb) bsums[t] = s[t] - v;  // exclusive block bases
    if (t == 0) offs[N] = E;
}

__global__ void k_scan3(const int* __restrict__ deg, const int* __restrict__ bsums,
                        int* __restrict__ offs, int N) {
    __shared__ int s[256];
    int i = blockIdx.x * 256 + threadIdx.x;
    int v = (i < N) ? deg[i] : 0;
    s[threadIdx.x] = v;
    __syncthreads();
    for (int off = 1; off < 256; off <<= 1) {
        int add = (threadIdx.x >= off) ? s[threadIdx.x - off] : 0;
        __syncthreads();
        s[threadIdx.x] += add;
        __syncthreads();
    }
    if (i < N) offs[i] = bsums[blockIdx.x] + s[threadIdx.x] - v;
}

__global__ void k_fill(const int* __restrict__ row, const int* __restrict__ col,
                       const int* __restrict__ offs, int* __restrict__ cursor,
                       int* __restrict__ rows, int E) {
    int e = blockIdx.x * blockDim.x + threadIdx.x;
    if (e < E) {
        int c = col[e];
        int p = offs[c] + atomicAdd(&cursor[c], 1);
        rows[p] = row[e];
    }
}

// ---------------- dense compute ----------------

// m[N,64] = h[N,K] @ W[K,64].  16 nodes/block, 256 thr: lane=col, 4 nodes/thread.
template<int K>
__global__ void k_gemm(const float* __restrict__ h, const float* __restrict__ W,
                       float* __restrict__ m, int N) {
    __shared__ float sh[16][K];
    int block0 = blockIdx.x * 16;
    for (int idx = threadIdx.x; idx < 16 * K; idx += 256) {
        int nn = idx / K, kk = idx % K;
        int node = block0 + nn;
        sh[nn][kk] = (node < N) ? h[(size_t)node * K + kk] : 0.f;
    }
    __syncthreads();
    int colj = threadIdx.x & 63;
    int nl = threadIdx.x >> 6;  // 0..3 (uniform per wave -> LDS broadcast reads)
    float a0 = 0.f, a1 = 0.f, a2 = 0.f, a3 = 0.f;
    #pragma unroll 8
    for (int k = 0; k < K; k++) {
        float w = W[k * HID + colj];  // L1-resident (<=32KB)
        a0 += sh[nl][k] * w;
        a1 += sh[nl + 4][k] * w;
        a2 += sh[nl + 8][k] * w;
        a3 += sh[nl + 12][k] * w;
    }
    int n0 = block0 + nl;
    if (n0 < N)      m[(size_t)n0 * HID + colj] = a0;
    if (n0 + 4 < N)  m[(size_t)(n0 + 4) * HID + colj] = a1;
    if (n0 + 8 < N)  m[(size_t)(n0 + 8) * HID + colj] = a2;
    if (n0 + 12 < N) m[(size_t)(n0 + 12) * HID + colj] = a3;
}

// agg[i,:] = sum_{e: col=i} m[row_e,:]*dinv[i]*dinv[row_e] + m[i,:]*dinv[i]^2
// one wave per node, lane = feature.  No float atomics.
__global__ void k_agg(const float* __restrict__ m, const float* __restrict__ dinv,
                      const int* __restrict__ offs, const int* __restrict__ rows,
                      float* __restrict__ agg, int N) {
    int node = (int)((blockIdx.x * (size_t)blockDim.x + threadIdx.x) >> 6);
    int lane = threadIdx.x & 63;
    if (node >= N) return;
    float di = dinv[node];
    float acc = m[(size_t)node * HID + lane] * di * di;
    int s = offs[node], e = offs[node + 1];
    for (int j = s; j < e; j++) {
        int r = rows[j];
        acc += m[(size_t)r * HID + lane] * (di * dinv[r]);
    }
    agg[(size_t)node * HID + lane] = acc;
}

// per-feature sum and sumsq -> stats[0:64]=sum, stats[64:128]=sumsq
__global__ void k_stats(const float* __restrict__ agg, float* __restrict__ stats, int N) {
    int f = threadIdx.x & 63;
    int part = threadIdx.x >> 6;  // 0..3
    float s = 0.f, sq = 0.f;
    for (int node = blockIdx.x * 4 + part; node < N; node += gridDim.x * 4) {
        float v = agg[(size_t)node * HID + f];
        s += v; sq += v * v;
    }
    __shared__ float ss[4][64], sg[4][64];
    ss[part][f] = s; sg[part][f] = sq;
    __syncthreads();
    if (part == 0) {
        s  = ss[0][f] + ss[1][f] + ss[2][f] + ss[3][f];
        sq = sg[0][f] + sg[1][f] + sg[2][f] + sg[3][f];
        atomicAdd(&stats[f], s);
        atomicAdd(&stats[64 + f], sq);
    }
}

// out = relu((agg-mean)*g*rsqrt(var+eps)+be [+ res]).  (GCN bias b cancels in BN.)
__global__ void k_bnapply(const float* __restrict__ agg, const float* __restrict__ res,
                          const float* __restrict__ stats, const float* __restrict__ gamma,
                          const float* __restrict__ beta, float* __restrict__ out,
                          int N, int hasRes) {
    const float invN = 1.0f / (float)N;
    size_t total = (size_t)N * HID;
    for (size_t idx = blockIdx.x * (size_t)blockDim.x + threadIdx.x; idx < total;
         idx += (size_t)gridDim.x * blockDim.x) {
        int f = (int)(idx & 63);
        float mean = stats[f] * invN;
        float var = stats[64 + f] * invN - mean * mean;
        float sc = gamma[f] * rsqrtf(var + BN_EPS);
        float v = (agg[idx] - mean) * sc + beta[f];
        if (hasRes) v += res[idx];
        out[idx] = fmaxf(v, 0.f);
    }
}

// sorted-batch run-length pooling: 1 wave per 64-node chunk, lane = feature.
__global__ void k_pool(const float* __restrict__ h, const int* __restrict__ batch,
                       float* __restrict__ pooled, float* __restrict__ gcnt, int N) {
    int lane = threadIdx.x;  // blockDim = 64
    int start = blockIdx.x * 64;
    if (start >= N) return;
    int end = min(start + 64, N);
    int gcur = batch[start];
    float acc = 0.f; int run = 0;
    for (int n = start; n < end; n++) {
        int g = batch[n];
        if (g != gcur) {
            atomicAdd(&pooled[gcur * HID + lane], acc);
            if (lane == 0) atomicAdd(&gcnt[gcur], (float)run);
            acc = 0.f; run = 0; gcur = g;
        }
        acc += h[(size_t)n * HID + lane];
        run++;
    }
    atomicAdd(&pooled[gcur * HID + lane], acc);
    if (lane == 0) atomicAdd(&gcnt[gcur], (float)run);
}

// out[g] = dot(pooled[g]/max(cnt,1), fcw) + fcb.  wave per graph.
__global__ void k_final(const float* __restrict__ pooled, const float* __restrict__ gcnt,
                        const float* __restrict__ fcw, const float* __restrict__ fcb,
                        float* __restrict__ out) {
    int g = (int)((blockIdx.x * (size_t)blockDim.x + threadIdx.x) >> 6);
    int lane = threadIdx.x & 63;
    if (g >= NG) return;
    float c = fmaxf(gcnt[g], 1.f);
    float v = pooled[g * HID + lane] / c * fcw[lane];
    for (int off = 32; off > 0; off >>= 1) v += __shfl_down(v, off, 64);
    if (lane == 0) out[g] = v + fcb[0];
}

// ---------------- launch ----------------

extern "C" void kernel_launch(void* const* d_in, const int* in_sizes, int n_in,
                              void* d_out, int out_size, void* d_ws, size_t ws_size,
                              hipStream_t stream) {
    const float* x    = (const float*)d_in[0];
    const int*   ei   = (const int*)d_in[1];
    const int*   batch= (const int*)d_in[2];
    const float* w1   = (const float*)d_in[3];
    const float* g1   = (const float*)d_in[5];
    const float* be1  = (const float*)d_in[6];
    const float* w2   = (const float*)d_in[7];
    const float* g2   = (const float*)d_in[9];
    const float* be2  = (const float*)d_in[10];
    const float* w3   = (const float*)d_in[11];
    const float* g3   = (const float*)d_in[13];
    const float* be3  = (const float*)d_in[14];
    const float* fcw  = (const float*)d_in[15];
    const float* fcb  = (const float*)d_in[16];
    float* out = (float*)d_out;

    const int N = NN, E = NE;
    const int* erow = ei;       // edge_index[0] = source
    const int* ecol = ei + E;   // edge_index[1] = target

    char* ws = (char*)d_ws;
    size_t off = 0;
    auto alloc = [&](size_t bytes) -> char* {
        char* p = ws + off;
        off = (off + bytes + 255) & ~(size_t)255;
        return p;
    };
    int*   deg    = (int*)alloc((size_t)N * 4);
    float* dinv   = (float*)alloc((size_t)N * 4);
    int*   offs   = (int*)alloc((size_t)(N + 1) * 4);
    int*   cursor = (int*)alloc((size_t)N * 4);
    int*   bsums  = (int*)alloc(512 * 4);
    int*   rows   = (int*)alloc((size_t)E * 4);
    float* bufA   = (float*)alloc((size_t)N * HID * 4);  // m
    float* bufB   = (float*)alloc((size_t)N * HID * 4);  // agg
    float* bufC   = (float*)alloc((size_t)N * HID * 4);  // h1 (res) / h3
    float* bufD   = (float*)alloc((size_t)N * HID * 4);  // h2
    float* stats  = (float*)alloc(3 * 128 * 4);
    float* pooled = (float*)alloc((size_t)NG * HID * 4);
    float* gcnt   = (float*)alloc((size_t)NG * 4);
    (void)ws_size; (void)in_sizes; (void)n_in; (void)out_size;

    hipMemsetAsync(deg, 0, (size_t)N * 4, stream);
    hipMemsetAsync(cursor, 0, (size_t)N * 4, stream);
    hipMemsetAsync(stats, 0, 3 * 128 * 4, stream);
    hipMemsetAsync(pooled, 0, (size_t)NG * HID * 4, stream);
    hipMemsetAsync(gcnt, 0, (size_t)NG * 4, stream);

    const int nbN = (N + 255) / 256;       // 391
    const int nbE = (E + 255) / 256;       // 6250
    const int nbNode16 = (N + 15) / 16;    // 6250
    const int nbElem = (int)(((size_t)N * HID + 255) / 256);  // 25000

    k_deg<<<nbE, 256, 0, stream>>>(ecol, deg, E);
    k_dinv<<<nbN, 256, 0, stream>>>(deg, dinv, N);
    k_scan1<<<nbN, 256, 0, stream>>>(deg, bsums, N);
    k_scan2<<<1, 512, 0, stream>>>(bsums, nbN, offs, N, E);
    k_scan3<<<nbN, 256, 0, stream>>>(deg, bsums, offs, N);
    k_fill<<<nbE, 256, 0, stream>>>(erow, ecol, offs, cursor, rows, E);

    // layer 1: x[N,128] -> bufC (=res)
    k_gemm<INDIM><<<nbNode16, 256, 0, stream>>>(x, w1, bufA, N);
    k_agg<<<nbElem, 256, 0, stream>>>(bufA, dinv, offs, rows, bufB, N);
    k_stats<<<400, 256, 0, stream>>>(bufB, stats, N);
    k_bnapply<<<nbElem, 256, 0, stream>>>(bufB, nullptr, stats, g1, be1, bufC, N, 0);

    // layer 2: bufC -> bufD  (residual add bufC)
    k_gemm<HID><<<nbNode16, 256, 0, stream>>>(bufC, w2, bufA, N);
    k_agg<<<nbElem, 256, 0, stream>>>(bufA, dinv, offs, rows, bufB, N);
    k_stats<<<400, 256, 0, stream>>>(bufB, stats + 128, N);
    k_bnapply<<<nbElem, 256, 0, stream>>>(bufB, bufC, stats + 128, g2, be2, bufD, N, 1);

    // layer 3: bufD -> bufC
    k_gemm<HID><<<nbNode16, 256, 0, stream>>>(bufD, w3, bufA, N);
    k_agg<<<nbElem, 256, 0, stream>>>(bufA, dinv, offs, rows, bufB, N);
    k_stats<<<400, 256, 0, stream>>>(bufB, stats + 256, N);
    k_bnapply<<<nbElem, 256, 0, stream>>>(bufB, nullptr, stats + 256, g3, be3, bufC, N, 0);

    // pool + final
    k_pool<<<(N + 63) / 64, 64, 0, stream>>>(bufC, batch, pooled, gcnt, N);
    k_final<<<(NG * 64) / 256, 256, 0, stream>>>(pooled, gcnt, fcw, fcb, out);
}

// Round 2
// 715.035 us; speedup vs baseline: 1.3347x; 1.3347x over previous
//
#include <hip/hip_runtime.h>

#define NN 100000
#define NE 1600000
#define INDIM 128
#define HID 64
#define NG 1024
#define BN_EPS 1e-5f

typedef unsigned short u16;
typedef unsigned int u32;

__device__ __forceinline__ u16 f2bf(float f) {
    u32 u = __float_as_uint(f);
    u32 r = (u + 0x7fffu + ((u >> 16) & 1u)) >> 16;   // RNE
    return (u16)r;
}
__device__ __forceinline__ float bf2f(u16 b) {
    return __uint_as_float(((u32)b) << 16);
}

// ---------------- graph preprocessing ----------------

__global__ void k_deg(const int* __restrict__ col, int* __restrict__ deg, int E) {
    int e = blockIdx.x * blockDim.x + threadIdx.x;
    if (e < E) atomicAdd(&deg[col[e]], 1);
}

__global__ void k_dinv(const int* __restrict__ deg, float* __restrict__ dinv, int N) {
    int i = blockIdx.x * blockDim.x + threadIdx.x;
    if (i < N) dinv[i] = rsqrtf((float)(deg[i] + 1));  // +1 = self-loop
}

__global__ void k_scan1(const int* __restrict__ deg, int* __restrict__ bsums, int N) {
    __shared__ int s[256];
    int i = blockIdx.x * 256 + threadIdx.x;
    s[threadIdx.x] = (i < N) ? deg[i] : 0;
    __syncthreads();
    for (int off = 128; off > 0; off >>= 1) {
        if (threadIdx.x < off) s[threadIdx.x] += s[threadIdx.x + off];
        __syncthreads();
    }
    if (threadIdx.x == 0) bsums[blockIdx.x] = s[0];
}

__global__ void k_scan2(int* __restrict__ bsums, int nb, int* __restrict__ offs, int N, int E) {
    __shared__ int s[512];
    int t = threadIdx.x;
    int v = (t < nb) ? bsums[t] : 0;
    s[t] = v;
    __syncthreads();
    for (int off = 1; off < 512; off <<= 1) {
        int add = (t >= off) ? s[t - off] : 0;
        __syncthreads();
        s[t] += add;
        __syncthreads();
    }
    if (t < nb) bsums[t] = s[t] - v;  // exclusive block bases
    if (t == 0) offs[N] = E;
}

__global__ void k_scan3(const int* __restrict__ deg, const int* __restrict__ bsums,
                        int* __restrict__ offs, int N) {
    __shared__ int s[256];
    int i = blockIdx.x * 256 + threadIdx.x;
    int v = (i < N) ? deg[i] : 0;
    s[threadIdx.x] = v;
    __syncthreads();
    for (int off = 1; off < 256; off <<= 1) {
        int add = (threadIdx.x >= off) ? s[threadIdx.x - off] : 0;
        __syncthreads();
        s[threadIdx.x] += add;
        __syncthreads();
    }
    if (i < N) offs[i] = bsums[blockIdx.x] + s[threadIdx.x] - v;
}

__global__ void k_fill(const int* __restrict__ row, const int* __restrict__ col,
                       const int* __restrict__ offs, int* __restrict__ cursor,
                       int* __restrict__ rows, int E) {
    int e = blockIdx.x * blockDim.x + threadIdx.x;
    if (e < E) {
        int c = col[e];
        int p = offs[c] + atomicAdd(&cursor[c], 1);
        rows[p] = row[e];
    }
}

// ---------------- dense compute ----------------

// m'[node,64] = bf16( (h[node,:]@W) * dinv[node] ).  16 nodes/block, 256 thr.
template<int K>
__global__ void k_gemm(const float* __restrict__ h, const float* __restrict__ W,
                       const float* __restrict__ dinv, u16* __restrict__ m, int N) {
    __shared__ float sh[16][K];
    int block0 = blockIdx.x * 16;
    for (int idx = threadIdx.x; idx < 16 * K; idx += 256) {
        int nn = idx / K, kk = idx % K;
        int node = block0 + nn;
        sh[nn][kk] = (node < N) ? h[(size_t)node * K + kk] : 0.f;
    }
    __syncthreads();
    int colj = threadIdx.x & 63;
    int nl = threadIdx.x >> 6;  // 0..3 (uniform per wave -> LDS broadcast reads)
    float a0 = 0.f, a1 = 0.f, a2 = 0.f, a3 = 0.f;
    #pragma unroll 8
    for (int k = 0; k < K; k++) {
        float w = W[k * HID + colj];  // L1-resident (<=32KB)
        a0 += sh[nl][k] * w;
        a1 += sh[nl + 4][k] * w;
        a2 += sh[nl + 8][k] * w;
        a3 += sh[nl + 12][k] * w;
    }
    int n0 = block0 + nl;
    if (n0 < N)      m[(size_t)n0 * HID + colj]        = f2bf(a0 * dinv[n0]);
    if (n0 + 4 < N)  m[(size_t)(n0 + 4) * HID + colj]  = f2bf(a1 * dinv[n0 + 4]);
    if (n0 + 8 < N)  m[(size_t)(n0 + 8) * HID + colj]  = f2bf(a2 * dinv[n0 + 8]);
    if (n0 + 12 < N) m[(size_t)(n0 + 12) * HID + colj] = f2bf(a3 * dinv[n0 + 12]);
}

// agg[i,:] = dinv[i] * ( m'[i,:] + sum_{e: col=i} m'[row_e,:] )
// one wave per node, lane = feature.  bf16 gathers = 128B/row = 1 line.
__global__ void k_agg(const u16* __restrict__ m, const float* __restrict__ dinv,
                      const int* __restrict__ offs, const int* __restrict__ rows,
                      float* __restrict__ agg, int N) {
    int node = (int)((blockIdx.x * (size_t)blockDim.x + threadIdx.x) >> 6);
    int lane = threadIdx.x & 63;
    if (node >= N) return;
    float di = dinv[node];
    float acc = bf2f(m[(size_t)node * HID + lane]);
    int s = offs[node], e = offs[node + 1];
    #pragma unroll 4
    for (int j = s; j < e; j++) {
        int r = rows[j];
        acc += bf2f(m[(size_t)r * HID + lane]);
    }
    agg[(size_t)node * HID + lane] = acc * di;
}

// per-feature sum and sumsq -> stats[0:64]=sum, stats[64:128]=sumsq
__global__ void k_stats(const float* __restrict__ agg, float* __restrict__ stats, int N) {
    int f = threadIdx.x & 63;
    int part = threadIdx.x >> 6;  // 0..3
    float s = 0.f, sq = 0.f;
    for (int node = blockIdx.x * 4 + part; node < N; node += gridDim.x * 4) {
        float v = agg[(size_t)node * HID + f];
        s += v; sq += v * v;
    }
    __shared__ float ss[4][64], sg[4][64];
    ss[part][f] = s; sg[part][f] = sq;
    __syncthreads();
    if (part == 0) {
        s  = ss[0][f] + ss[1][f] + ss[2][f] + ss[3][f];
        sq = sg[0][f] + sg[1][f] + sg[2][f] + sg[3][f];
        atomicAdd(&stats[f], s);
        atomicAdd(&stats[64 + f], sq);
    }
}

// out = relu((agg-mean)*g*rsqrt(var+eps)+be [+ res]).  (GCN bias b cancels in BN.)
__global__ void k_bnapply(const float* __restrict__ agg, const float* __restrict__ res,
                          const float* __restrict__ stats, const float* __restrict__ gamma,
                          const float* __restrict__ beta, float* __restrict__ out,
                          int N, int hasRes) {
    const float invN = 1.0f / (float)N;
    size_t total = (size_t)N * HID;
    for (size_t idx = blockIdx.x * (size_t)blockDim.x + threadIdx.x; idx < total;
         idx += (size_t)gridDim.x * blockDim.x) {
        int f = (int)(idx & 63);
        float mean = stats[f] * invN;
        float var = stats[64 + f] * invN - mean * mean;
        float sc = gamma[f] * rsqrtf(var + BN_EPS);
        float v = (agg[idx] - mean) * sc + beta[f];
        if (hasRes) v += res[idx];
        out[idx] = fmaxf(v, 0.f);
    }
}

// sorted-batch run-length pooling: 1 wave per 64-node chunk, lane = feature.
__global__ void k_pool(const float* __restrict__ h, const int* __restrict__ batch,
                       float* __restrict__ pooled, float* __restrict__ gcnt, int N) {
    int lane = threadIdx.x;  // blockDim = 64
    int start = blockIdx.x * 64;
    if (start >= N) return;
    int end = min(start + 64, N);
    int gcur = batch[start];
    float acc = 0.f; int run = 0;
    for (int n = start; n < end; n++) {
        int g = batch[n];
        if (g != gcur) {
            atomicAdd(&pooled[gcur * HID + lane], acc);
            if (lane == 0) atomicAdd(&gcnt[gcur], (float)run);
            acc = 0.f; run = 0; gcur = g;
        }
        acc += h[(size_t)n * HID + lane];
        run++;
    }
    atomicAdd(&pooled[gcur * HID + lane], acc);
    if (lane == 0) atomicAdd(&gcnt[gcur], (float)run);
}

// out[g] = dot(pooled[g]/max(cnt,1), fcw) + fcb.  wave per graph.
__global__ void k_final(const float* __restrict__ pooled, const float* __restrict__ gcnt,
                        const float* __restrict__ fcw, const float* __restrict__ fcb,
                        float* __restrict__ out) {
    int g = (int)((blockIdx.x * (size_t)blockDim.x + threadIdx.x) >> 6);
    int lane = threadIdx.x & 63;
    if (g >= NG) return;
    float c = fmaxf(gcnt[g], 1.f);
    float v = pooled[g * HID + lane] / c * fcw[lane];
    for (int off = 32; off > 0; off >>= 1) v += __shfl_down(v, off, 64);
    if (lane == 0) out[g] = v + fcb[0];
}

// ---------------- launch ----------------

extern "C" void kernel_launch(void* const* d_in, const int* in_sizes, int n_in,
                              void* d_out, int out_size, void* d_ws, size_t ws_size,
                              hipStream_t stream) {
    const float* x    = (const float*)d_in[0];
    const int*   ei   = (const int*)d_in[1];
    const int*   batch= (const int*)d_in[2];
    const float* w1   = (const float*)d_in[3];
    const float* g1   = (const float*)d_in[5];
    const float* be1  = (const float*)d_in[6];
    const float* w2   = (const float*)d_in[7];
    const float* g2   = (const float*)d_in[9];
    const float* be2  = (const float*)d_in[10];
    const float* w3   = (const float*)d_in[11];
    const float* g3   = (const float*)d_in[13];
    const float* be3  = (const float*)d_in[14];
    const float* fcw  = (const float*)d_in[15];
    const float* fcb  = (const float*)d_in[16];
    float* out = (float*)d_out;

    const int N = NN, E = NE;
    const int* erow = ei;       // edge_index[0] = source
    const int* ecol = ei + E;   // edge_index[1] = target

    char* ws = (char*)d_ws;
    size_t off = 0;
    auto alloc = [&](size_t bytes) -> char* {
        char* p = ws + off;
        off = (off + bytes + 255) & ~(size_t)255;
        return p;
    };
    int*   deg    = (int*)alloc((size_t)N * 4);
    float* dinv   = (float*)alloc((size_t)N * 4);
    int*   offs   = (int*)alloc((size_t)(N + 1) * 4);
    int*   cursor = (int*)alloc((size_t)N * 4);
    int*   bsums  = (int*)alloc(512 * 4);
    int*   rows   = (int*)alloc((size_t)E * 4);
    u16*   bufM   = (u16*)alloc((size_t)N * HID * 2);   // m' (bf16, dinv-scaled)
    float* bufB   = (float*)alloc((size_t)N * HID * 4); // agg
    float* bufC   = (float*)alloc((size_t)N * HID * 4); // h1 (res) / h3
    float* bufD   = (float*)alloc((size_t)N * HID * 4); // h2
    float* stats  = (float*)alloc(3 * 128 * 4);
    float* pooled = (float*)alloc((size_t)NG * HID * 4);
    float* gcnt   = (float*)alloc((size_t)NG * 4);
    (void)ws_size; (void)in_sizes; (void)n_in; (void)out_size;

    hipMemsetAsync(deg, 0, (size_t)N * 4, stream);
    hipMemsetAsync(cursor, 0, (size_t)N * 4, stream);
    hipMemsetAsync(stats, 0, 3 * 128 * 4, stream);
    hipMemsetAsync(pooled, 0, (size_t)NG * HID * 4, stream);
    hipMemsetAsync(gcnt, 0, (size_t)NG * 4, stream);

    const int nbN = (N + 255) / 256;       // 391
    const int nbE = (E + 255) / 256;       // 6250
    const int nbNode16 = (N + 15) / 16;    // 6250
    const int nbElem = (int)(((size_t)N * HID + 255) / 256);  // 25000

    k_deg<<<nbE, 256, 0, stream>>>(ecol, deg, E);
    k_dinv<<<nbN, 256, 0, stream>>>(deg, dinv, N);
    k_scan1<<<nbN, 256, 0, stream>>>(deg, bsums, N);
    k_scan2<<<1, 512, 0, stream>>>(bsums, nbN, offs, N, E);
    k_scan3<<<nbN, 256, 0, stream>>>(deg, bsums, offs, N);
    k_fill<<<nbE, 256, 0, stream>>>(erow, ecol, offs, cursor, rows, E);

    // layer 1: x[N,128] -> bufC (=res)
    k_gemm<INDIM><<<nbNode16, 256, 0, stream>>>(x, w1, dinv, bufM, N);
    k_agg<<<nbElem, 256, 0, stream>>>(bufM, dinv, offs, rows, bufB, N);
    k_stats<<<400, 256, 0, stream>>>(bufB, stats, N);
    k_bnapply<<<nbElem, 256, 0, stream>>>(bufB, nullptr, stats, g1, be1, bufC, N, 0);

    // layer 2: bufC -> bufD  (residual add bufC)
    k_gemm<HID><<<nbNode16, 256, 0, stream>>>(bufC, w2, dinv, bufM, N);
    k_agg<<<nbElem, 256, 0, stream>>>(bufM, dinv, offs, rows, bufB, N);
    k_stats<<<400, 256, 0, stream>>>(bufB, stats + 128, N);
    k_bnapply<<<nbElem, 256, 0, stream>>>(bufB, bufC, stats + 128, g2, be2, bufD, N, 1);

    // layer 3: bufD -> bufC
    k_gemm<HID><<<nbNode16, 256, 0, stream>>>(bufD, w3, dinv, bufM, N);
    k_agg<<<nbElem, 256, 0, stream>>>(bufM, dinv, offs, rows, bufB, N);
    k_stats<<<400, 256, 0, stream>>>(bufB, stats + 256, N);
    k_bnapply<<<nbElem, 256, 0, stream>>>(bufB, nullptr, stats + 256, g3, be3, bufC, N, 0);

    // pool + final
    k_pool<<<(N + 63) / 64, 64, 0, stream>>>(bufC, batch, pooled, gcnt, N);
    k_final<<<(NG * 64) / 256, 256, 0, stream>>>(pooled, gcnt, fcw, fcb, out);
}